// Round 4
// baseline (2176.302 us; speedup 1.0000x reference)
//
#include <hip/hip_runtime.h>

typedef short short8 __attribute__((ext_vector_type(8)));
typedef float f32x4 __attribute__((ext_vector_type(4)));

#define NE 1024
#define D 64
#define HW 4096
#define NTOK 65536
#define MARGIN 3.0e-3f

// ws layout (bytes)
#define WS_BN    0           // 1024 f32
#define WS_KEYS  4096        // 65536 u64
#define WS_EBF   528384      // 65536 u16 (bf16 bits of codebook)
#define WS_CNT   659456      // u32 counter
#define WS_CAND  659472      // u32 entries: (tok<<10)|k

__device__ __forceinline__ unsigned short f2bf(float f) {   // RNE f32->bf16
    unsigned u = __float_as_uint(f);
    return (unsigned short)((u + 0x7fffu + ((u >> 16) & 1u)) >> 16);
}

// numpy pairwise sum of squares, n=64 (frozen — verified absmax=0 in R2)
__device__ __forceinline__ float np_sum64_sq(const float* v) {
    float s[8];
#pragma unroll
    for (int j = 0; j < 8; ++j) s[j] = __fmul_rn(v[j], v[j]);
#pragma unroll
    for (int i = 8; i < 64; i += 8) {
#pragma unroll
        for (int j = 0; j < 8; ++j)
            s[j] = __fadd_rn(s[j], __fmul_rn(v[i + j], v[i + j]));
    }
    return __fadd_rn(__fadd_rn(__fadd_rn(s[0], s[1]), __fadd_rn(s[2], s[3])),
                     __fadd_rn(__fadd_rn(s[4], s[5]), __fadd_rn(s[6], s[7])));
}

__global__ void k0_prep(const float* __restrict__ cb, float* __restrict__ bn,
                        unsigned short* __restrict__ ebf,
                        unsigned long long* __restrict__ keys,
                        unsigned int* __restrict__ cnt) {
    int gid = blockIdx.x * 256 + threadIdx.x;   // 65536 threads
    keys[gid] = ~0ULL;
    ebf[gid] = f2bf(cb[gid]);
    if (gid < NE) {
        float row[D];
        const float4* r4 = reinterpret_cast<const float4*>(cb + (size_t)gid * D);
#pragma unroll
        for (int i = 0; i < 16; ++i) {
            float4 v = r4[i];
            row[4*i+0] = v.x; row[4*i+1] = v.y; row[4*i+2] = v.z; row[4*i+3] = v.w;
        }
        bn[gid] = np_sum64_sq(row);
    }
    if (gid == 0) *cnt = 0;
}

__global__ __launch_bounds__(256) void k1_score(
        const float* __restrict__ in, const unsigned short* __restrict__ ebf,
        const float* __restrict__ bn_g, unsigned int* __restrict__ cnt,
        unsigned int* __restrict__ cand, unsigned int cap) {
    __shared__ unsigned short ebq[256 * 64];   // 32 KiB: one codebook quarter, swizzled
    __shared__ float sbn[NE];                  // 4 KiB

    const int tid  = threadIdx.x;
    const int w    = tid >> 6;
    const int lane = tid & 63;
    const int lcol = lane & 15;
    const int lhi  = lane >> 4;
    const int lrow = lhi * 4;

    const int tokw = blockIdx.x * 128 + w * 32;  // wave's 32 tokens (same batch b)
    const int b    = tokw >> 12;
    const int hwb  = tokw & 4095;

    for (int i = tid; i < NE; i += 256) sbn[i] = bn_g[i];

    // B fragments (registers, live whole kernel): lane holds X[tok][kb..kb+7]
    const float* xbase = in + (size_t)b * (D * HW);
    short8 B00, B01, B10, B11;
    {
        const int hw0 = hwb + lcol, hw1 = hwb + 16 + lcol;
        const int kb  = lhi * 8;
        const float* p;
        p = xbase + (size_t)kb * HW + hw0;
#pragma unroll
        for (int j = 0; j < 8; ++j) B00[j] = (short)f2bf(p[(size_t)j * HW]);
        p = xbase + (size_t)(kb + 32) * HW + hw0;
#pragma unroll
        for (int j = 0; j < 8; ++j) B01[j] = (short)f2bf(p[(size_t)j * HW]);
        p = xbase + (size_t)kb * HW + hw1;
#pragma unroll
        for (int j = 0; j < 8; ++j) B10[j] = (short)f2bf(p[(size_t)j * HW]);
        p = xbase + (size_t)(kb + 32) * HW + hw1;
#pragma unroll
        for (int j = 0; j < 8; ++j) B11[j] = (short)f2bf(p[(size_t)j * HW]);
    }

    const int swz   = (lcol & 7) << 4;
    const int aoff0 = lcol * 128 + ((lhi * 16) ^ swz);         // k-half 0
    const int aoff1 = lcol * 128 + ((64 + lhi * 16) ^ swz);    // k-half 1

    float v10 = 3.402823466e+38f, v11 = 3.402823466e+38f;

    // ---- PASS 1: per-token bf16 min ----
    for (int q = 0; q < 4; ++q) {
        __syncthreads();
        const char* src = (const char*)ebf + q * 32768;
#pragma unroll
        for (int i = 0; i < 8; ++i) {
            int L = (tid + i * 256) * 16;
            int row = L >> 7, wi = L & 127;
            int4 v = *(const int4*)(src + L);
            *(int4*)((char*)ebq + row * 128 + (wi ^ ((row & 7) << 4))) = v;
        }
        __syncthreads();
#pragma unroll
        for (int ct = 0; ct < 16; ++ct) {
            const char* lp = (const char*)ebq + ct * 2048;
            short8 A0 = *(const short8*)(lp + aoff0);
            short8 A1 = *(const short8*)(lp + aoff1);
            f32x4 bnv = *(const f32x4*)(sbn + q * 256 + ct * 16 + lrow);
            f32x4 acc = {0.f, 0.f, 0.f, 0.f};
            acc = __builtin_amdgcn_mfma_f32_16x16x32_bf16(A0, B00, acc, 0, 0, 0);
            acc = __builtin_amdgcn_mfma_f32_16x16x32_bf16(A1, B01, acc, 0, 0, 0);
#pragma unroll
            for (int r = 0; r < 4; ++r)
                v10 = fminf(v10, __fmaf_rn(-2.0f, acc[r], bnv[r]));
            f32x4 ac2 = {0.f, 0.f, 0.f, 0.f};
            ac2 = __builtin_amdgcn_mfma_f32_16x16x32_bf16(A0, B10, ac2, 0, 0, 0);
            ac2 = __builtin_amdgcn_mfma_f32_16x16x32_bf16(A1, B11, ac2, 0, 0, 0);
#pragma unroll
            for (int r = 0; r < 4; ++r)
                v11 = fminf(v11, __fmaf_rn(-2.0f, ac2[r], bnv[r]));
        }
    }

    // token-wide min across the 4 lane-groups sharing a column
    v10 = fminf(v10, __shfl_xor(v10, 16));
    v10 = fminf(v10, __shfl_xor(v10, 32));
    v11 = fminf(v11, __shfl_xor(v11, 16));
    v11 = fminf(v11, __shfl_xor(v11, 32));
    const float thr0 = v10 + MARGIN;
    const float thr1 = v11 + MARGIN;
    const unsigned int tokA = (unsigned)(tokw + lcol);
    const unsigned int tokB = tokA + 16u;

    // ---- PASS 2: recompute, collect candidates within margin ----
    for (int q = 0; q < 4; ++q) {
        __syncthreads();
        const char* src = (const char*)ebf + q * 32768;
#pragma unroll
        for (int i = 0; i < 8; ++i) {
            int L = (tid + i * 256) * 16;
            int row = L >> 7, wi = L & 127;
            int4 v = *(const int4*)(src + L);
            *(int4*)((char*)ebq + row * 128 + (wi ^ ((row & 7) << 4))) = v;
        }
        __syncthreads();
#pragma unroll
        for (int ct = 0; ct < 16; ++ct) {
            const char* lp = (const char*)ebq + ct * 2048;
            short8 A0 = *(const short8*)(lp + aoff0);
            short8 A1 = *(const short8*)(lp + aoff1);
            f32x4 bnv = *(const f32x4*)(sbn + q * 256 + ct * 16 + lrow);
            f32x4 acc = {0.f, 0.f, 0.f, 0.f};
            acc = __builtin_amdgcn_mfma_f32_16x16x32_bf16(A0, B00, acc, 0, 0, 0);
            acc = __builtin_amdgcn_mfma_f32_16x16x32_bf16(A1, B01, acc, 0, 0, 0);
            f32x4 ac2 = {0.f, 0.f, 0.f, 0.f};
            ac2 = __builtin_amdgcn_mfma_f32_16x16x32_bf16(A0, B10, ac2, 0, 0, 0);
            ac2 = __builtin_amdgcn_mfma_f32_16x16x32_bf16(A1, B11, ac2, 0, 0, 0);
            const int kub = q * 256 + ct * 16 + lrow;   // lane's base code index
#pragma unroll
            for (int r = 0; r < 4; ++r) {
                {
                    float t = __fmaf_rn(-2.0f, acc[r], bnv[r]);
                    bool pr = (t <= thr0);
                    unsigned long long m = __ballot(pr);
                    if (m) {
                        int leader = (int)__builtin_ctzll(m);
                        unsigned int base = 0;
                        if (lane == leader) base = atomicAdd(cnt, (unsigned)__popcll(m));
                        base = (unsigned)__shfl((int)base, leader);
                        if (pr) {
                            unsigned pos = base + (unsigned)__popcll(m & ((1ull << lane) - 1ull));
                            if (pos < cap) cand[pos] = (tokA << 10) | (unsigned)(kub + r);
                        }
                    }
                }
                {
                    float t = __fmaf_rn(-2.0f, ac2[r], bnv[r]);
                    bool pr = (t <= thr1);
                    unsigned long long m = __ballot(pr);
                    if (m) {
                        int leader = (int)__builtin_ctzll(m);
                        unsigned int base = 0;
                        if (lane == leader) base = atomicAdd(cnt, (unsigned)__popcll(m));
                        base = (unsigned)__shfl((int)base, leader);
                        if (pr) {
                            unsigned pos = base + (unsigned)__popcll(m & ((1ull << lane) - 1ull));
                            if (pos < cap) cand[pos] = (tokB << 10) | (unsigned)(kub + r);
                        }
                    }
                }
            }
        }
    }
}

__global__ void k3_rerank(const float* __restrict__ in, const float* __restrict__ cb,
                          const float* __restrict__ bn, const unsigned int* __restrict__ cnt,
                          const unsigned int* __restrict__ cand,
                          unsigned long long* __restrict__ keys, unsigned int cap) {
    unsigned n = *cnt; if (n > cap) n = cap;
    unsigned stride = gridDim.x * blockDim.x;
    for (unsigned i = blockIdx.x * blockDim.x + threadIdx.x; i < n; i += stride) {
        unsigned e = cand[i];
        unsigned tok = e >> 10, k = e & 1023u;
        int b = tok >> 12, hw = tok & 4095;
        const float* x = in + (size_t)b * (D * HW) + hw;
        float xv[D];
#pragma unroll
        for (int d = 0; d < D; ++d) xv[d] = x[(size_t)d * HW];
        float a = np_sum64_sq(xv);                       // frozen
        const float* er = cb + (size_t)k * D;
        float dot = 0.f;                                 // frozen: sequential, ascending d
#pragma unroll
        for (int d = 0; d < D; ++d) dot = __fmaf_rn(xv[d], er[d], dot);
        float qv = __fsub_rn(__fadd_rn(a, bn[k]), __fmul_rn(2.0f, dot));  // frozen
        unsigned long long key = ((unsigned long long)__float_as_uint(qv) << 32) | k;
        atomicMin(&keys[tok], key);                      // (q, then k) lexicographic min
    }
}

__global__ void k4_gather(const float* __restrict__ cb,
                          const unsigned long long* __restrict__ keys,
                          float* __restrict__ out) {
    int tok = blockIdx.x * 256 + threadIdx.x;
    int b = tok >> 12, hw = tok & 4095;
    unsigned k = (unsigned)(keys[tok] & 0xFFFFFFFFull);
    float* ot = out + (size_t)b * (D * HW) + hw;
    const float4* er = reinterpret_cast<const float4*>(cb + (size_t)k * D);
#pragma unroll
    for (int i = 0; i < 16; ++i) {
        float4 e = er[i];
        ot[(size_t)(4*i+0) * HW] = e.x;
        ot[(size_t)(4*i+1) * HW] = e.y;
        ot[(size_t)(4*i+2) * HW] = e.z;
        ot[(size_t)(4*i+3) * HW] = e.w;
    }
}

extern "C" void kernel_launch(void* const* d_in, const int* in_sizes, int n_in,
                              void* d_out, int out_size, void* d_ws, size_t ws_size,
                              hipStream_t stream) {
    const float* in  = (const float*)d_in[0];
    const float* cb  = (const float*)d_in[1];
    float*       out = (float*)d_out;
    char*        ws  = (char*)d_ws;

    float*              bn   = (float*)(ws + WS_BN);
    unsigned long long* keys = (unsigned long long*)(ws + WS_KEYS);
    unsigned short*     ebf  = (unsigned short*)(ws + WS_EBF);
    unsigned int*       cnt  = (unsigned int*)(ws + WS_CNT);
    unsigned int*       cand = (unsigned int*)(ws + WS_CAND);

    size_t avail = (ws_size > (size_t)WS_CAND) ? (ws_size - WS_CAND) / 4 : 0;
    unsigned int cap = (unsigned int)(avail > 2097152 ? 2097152 : avail);

    hipLaunchKernelGGL(k0_prep,   dim3(256), dim3(256), 0, stream, cb, bn, ebf, keys, cnt);
    hipLaunchKernelGGL(k1_score,  dim3(512), dim3(256), 0, stream, in, ebf, bn, cnt, cand, cap);
    hipLaunchKernelGGL(k3_rerank, dim3(256), dim3(256), 0, stream, in, cb, bn, cnt, cand, keys, cap);
    hipLaunchKernelGGL(k4_gather, dim3(256), dim3(256), 0, stream, cb, keys, out);
}

// Round 5
// 93.933 us; speedup vs baseline: 23.1687x; 23.1687x over previous
//
#include <hip/hip_runtime.h>

typedef short short8 __attribute__((ext_vector_type(8)));
typedef float f32x4 __attribute__((ext_vector_type(4)));

#define NE 1024
#define D 64
#define HW 4096
#define NTOK 65536
#define MARGIN 4.0e-3f

// ws layout (bytes): bn f32[1024] @0 ; ebf u16[65536] @4096 ; win u16[65536] @135168
// mask: NTOK x 16 u64 = 8 MB -> lives in d_out (k3 fully overwrites d_out afterwards)
#define WS_BN   0
#define WS_EBF  4096
#define WS_WIN  135168

__device__ __forceinline__ unsigned short f2bf(float f) {   // RNE f32->bf16
    unsigned u = __float_as_uint(f);
    return (unsigned short)((u + 0x7fffu + ((u >> 16) & 1u)) >> 16);
}

// numpy pairwise sum of squares, n=64 (frozen — exact since R2)
__device__ __forceinline__ float np_sum64_sq(const float* v) {
    float s[8];
#pragma unroll
    for (int j = 0; j < 8; ++j) s[j] = __fmul_rn(v[j], v[j]);
#pragma unroll
    for (int i = 8; i < 64; i += 8) {
#pragma unroll
        for (int j = 0; j < 8; ++j)
            s[j] = __fadd_rn(s[j], __fmul_rn(v[i + j], v[i + j]));
    }
    return __fadd_rn(__fadd_rn(__fadd_rn(s[0], s[1]), __fadd_rn(s[2], s[3])),
                     __fadd_rn(__fadd_rn(s[4], s[5]), __fadd_rn(s[6], s[7])));
}

__global__ void k0_prep(const float* __restrict__ cb, float* __restrict__ bn,
                        unsigned short* __restrict__ ebf,
                        unsigned long long* __restrict__ mask) {
    int gid = blockIdx.x * 256 + threadIdx.x;   // 65536 threads
    ebf[gid] = f2bf(cb[gid]);
    // zero the 8 MB mask, coalesced int4 stores
    int4 z = {0, 0, 0, 0};
    int4* mz = (int4*)mask;
#pragma unroll
    for (int i = 0; i < 8; ++i) mz[gid + i * 65536] = z;
    if (gid < NE) {
        float row[D];
        const float4* r4 = reinterpret_cast<const float4*>(cb + (size_t)gid * D);
#pragma unroll
        for (int i = 0; i < 16; ++i) {
            float4 v = r4[i];
            row[4*i+0] = v.x; row[4*i+1] = v.y; row[4*i+2] = v.z; row[4*i+3] = v.w;
        }
        bn[gid] = np_sum64_sq(row);
    }
}

__global__ __launch_bounds__(256) void k1_score(
        const float* __restrict__ in, const unsigned short* __restrict__ ebf,
        const float* __restrict__ bn_g, unsigned long long* __restrict__ mask) {
    __shared__ unsigned short ebq[256 * 64];   // 32 KiB: one codebook quarter, swizzled
    __shared__ float sbn[NE];                  // 4 KiB

    const int tid  = threadIdx.x;
    const int w    = tid >> 6;
    const int lane = tid & 63;
    const int lcol = lane & 15;
    const int lhi  = lane >> 4;
    const int lrow = lhi * 4;

    const int tokw = blockIdx.x * 128 + w * 32;  // wave's 32 tokens (same batch b)
    const int b    = tokw >> 12;
    const int hwb  = tokw & 4095;

    for (int i = tid; i < NE; i += 256) sbn[i] = bn_g[i];

    // B fragments: lane holds X[tok][kb..kb+7] (verified layout, R4 absmax=0)
    const float* xbase = in + (size_t)b * (D * HW);
    short8 B00, B01, B10, B11;
    {
        const int hw0 = hwb + lcol, hw1 = hwb + 16 + lcol;
        const int kb  = lhi * 8;
        const float* p;
        p = xbase + (size_t)kb * HW + hw0;
#pragma unroll
        for (int j = 0; j < 8; ++j) B00[j] = (short)f2bf(p[(size_t)j * HW]);
        p = xbase + (size_t)(kb + 32) * HW + hw0;
#pragma unroll
        for (int j = 0; j < 8; ++j) B01[j] = (short)f2bf(p[(size_t)j * HW]);
        p = xbase + (size_t)kb * HW + hw1;
#pragma unroll
        for (int j = 0; j < 8; ++j) B10[j] = (short)f2bf(p[(size_t)j * HW]);
        p = xbase + (size_t)(kb + 32) * HW + hw1;
#pragma unroll
        for (int j = 0; j < 8; ++j) B11[j] = (short)f2bf(p[(size_t)j * HW]);
    }

    const int swz   = (lcol & 7) << 4;
    const int aoff0 = lcol * 128 + ((lhi * 16) ^ swz);         // k-half 0
    const int aoff1 = lcol * 128 + ((64 + lhi * 16) ^ swz);    // k-half 1

    float v10 = 3.402823466e+38f, v11 = 3.402823466e+38f;

    // ---- PASS 1: per-token bf16 min ----
    for (int q = 0; q < 4; ++q) {
        __syncthreads();
        const char* src = (const char*)ebf + q * 32768;
#pragma unroll
        for (int i = 0; i < 8; ++i) {
            int L = (tid + i * 256) * 16;
            int row = L >> 7, wi = L & 127;
            int4 v = *(const int4*)(src + L);
            *(int4*)((char*)ebq + row * 128 + (wi ^ ((row & 7) << 4))) = v;
        }
        __syncthreads();
#pragma unroll
        for (int ct = 0; ct < 16; ++ct) {
            const char* lp = (const char*)ebq + ct * 2048;
            short8 A0 = *(const short8*)(lp + aoff0);
            short8 A1 = *(const short8*)(lp + aoff1);
            f32x4 bnv = *(const f32x4*)(sbn + q * 256 + ct * 16 + lrow);
            f32x4 acc = {0.f, 0.f, 0.f, 0.f};
            acc = __builtin_amdgcn_mfma_f32_16x16x32_bf16(A0, B00, acc, 0, 0, 0);
            acc = __builtin_amdgcn_mfma_f32_16x16x32_bf16(A1, B01, acc, 0, 0, 0);
#pragma unroll
            for (int r = 0; r < 4; ++r)
                v10 = fminf(v10, __fmaf_rn(-2.0f, acc[r], bnv[r]));
            f32x4 ac2 = {0.f, 0.f, 0.f, 0.f};
            ac2 = __builtin_amdgcn_mfma_f32_16x16x32_bf16(A0, B10, ac2, 0, 0, 0);
            ac2 = __builtin_amdgcn_mfma_f32_16x16x32_bf16(A1, B11, ac2, 0, 0, 0);
#pragma unroll
            for (int r = 0; r < 4; ++r)
                v11 = fminf(v11, __fmaf_rn(-2.0f, ac2[r], bnv[r]));
        }
    }

    v10 = fminf(v10, __shfl_xor(v10, 16));
    v10 = fminf(v10, __shfl_xor(v10, 32));
    v11 = fminf(v11, __shfl_xor(v11, 16));
    v11 = fminf(v11, __shfl_xor(v11, 32));
    const float thr0 = v10 + MARGIN;
    const float thr1 = v11 + MARGIN;
    const unsigned int tokA = (unsigned)(tokw + lcol);
    const unsigned int tokB = tokA + 16u;

    // ---- PASS 2: recompute, mark candidates (fire-and-forget atomicOr) ----
    for (int q = 0; q < 4; ++q) {
        __syncthreads();
        const char* src = (const char*)ebf + q * 32768;
#pragma unroll
        for (int i = 0; i < 8; ++i) {
            int L = (tid + i * 256) * 16;
            int row = L >> 7, wi = L & 127;
            int4 v = *(const int4*)(src + L);
            *(int4*)((char*)ebq + row * 128 + (wi ^ ((row & 7) << 4))) = v;
        }
        __syncthreads();
#pragma unroll
        for (int ct = 0; ct < 16; ++ct) {
            const char* lp = (const char*)ebq + ct * 2048;
            short8 A0 = *(const short8*)(lp + aoff0);
            short8 A1 = *(const short8*)(lp + aoff1);
            f32x4 bnv = *(const f32x4*)(sbn + q * 256 + ct * 16 + lrow);
            f32x4 acc = {0.f, 0.f, 0.f, 0.f};
            acc = __builtin_amdgcn_mfma_f32_16x16x32_bf16(A0, B00, acc, 0, 0, 0);
            acc = __builtin_amdgcn_mfma_f32_16x16x32_bf16(A1, B01, acc, 0, 0, 0);
            f32x4 ac2 = {0.f, 0.f, 0.f, 0.f};
            ac2 = __builtin_amdgcn_mfma_f32_16x16x32_bf16(A0, B10, ac2, 0, 0, 0);
            ac2 = __builtin_amdgcn_mfma_f32_16x16x32_bf16(A1, B11, ac2, 0, 0, 0);
            const int kub = q * 256 + ct * 16 + lrow;
#pragma unroll
            for (int r = 0; r < 4; ++r) {
                const int k = kub + r;
                float t0 = __fmaf_rn(-2.0f, acc[r], bnv[r]);
                if (t0 <= thr0)
                    atomicOr(&mask[(size_t)tokA * 16 + (k >> 6)], 1ull << (k & 63));
                float t1 = __fmaf_rn(-2.0f, ac2[r], bnv[r]);
                if (t1 <= thr1)
                    atomicOr(&mask[(size_t)tokB * 16 + (k >> 6)], 1ull << (k & 63));
            }
        }
    }
}

__global__ __launch_bounds__(256, 4) void k2_rerank(
        const float* __restrict__ in, const float* __restrict__ cb,
        const float* __restrict__ bn, const unsigned long long* __restrict__ mask,
        unsigned short* __restrict__ win) {
    const int tok = blockIdx.x * 256 + threadIdx.x;
    const int b = tok >> 12, hw = tok & 4095;
    const float* x = in + (size_t)b * (D * HW) + hw;
    float xv[D];
#pragma unroll
    for (int d = 0; d < D; ++d) xv[d] = x[(size_t)d * HW];
    const float a = np_sum64_sq(xv);                 // frozen

    float bestq = 3.402823466e+38f;
    int   bestk = 0;
    for (int wd = 0; wd < 16; ++wd) {                // ascending word ...
        unsigned long long m = mask[(size_t)tok * 16 + wd];
        while (m) {
            int bit = (int)__builtin_ctzll(m);       // ... ascending bit -> ascending k
            m &= m - 1;
            int k = wd * 64 + bit;
            const float* er = cb + (size_t)k * D;
            float dot = 0.f;                         // frozen: sequential, ascending d
#pragma unroll
            for (int d = 0; d < D; ++d) dot = __fmaf_rn(xv[d], er[d], dot);
            float qv = __fsub_rn(__fadd_rn(a, bn[k]), __fmul_rn(2.0f, dot));  // frozen
            if (qv < bestq) { bestq = qv; bestk = k; }   // strict < : first-min
        }
    }
    win[tok] = (unsigned short)bestk;
}

__global__ void k3_gather(const float* __restrict__ cb,
                          const unsigned short* __restrict__ win,
                          float* __restrict__ out) {
    const int tok = blockIdx.x * 256 + threadIdx.x;
    const int b = tok >> 12, hw = tok & 4095;
    const unsigned k = win[tok];
    float* ot = out + (size_t)b * (D * HW) + hw;
    const float4* er = reinterpret_cast<const float4*>(cb + (size_t)k * D);
#pragma unroll
    for (int i = 0; i < 16; ++i) {
        float4 e = er[i];
        ot[(size_t)(4*i+0) * HW] = e.x;
        ot[(size_t)(4*i+1) * HW] = e.y;
        ot[(size_t)(4*i+2) * HW] = e.z;
        ot[(size_t)(4*i+3) * HW] = e.w;
    }
}

extern "C" void kernel_launch(void* const* d_in, const int* in_sizes, int n_in,
                              void* d_out, int out_size, void* d_ws, size_t ws_size,
                              hipStream_t stream) {
    const float* in  = (const float*)d_in[0];
    const float* cb  = (const float*)d_in[1];
    float*       out = (float*)d_out;
    char*        ws  = (char*)d_ws;

    float*              bn   = (float*)(ws + WS_BN);
    unsigned short*     ebf  = (unsigned short*)(ws + WS_EBF);
    unsigned short*     win  = (unsigned short*)(ws + WS_WIN);
    unsigned long long* mask = (unsigned long long*)d_out;   // 8 MB scratch inside d_out

    hipLaunchKernelGGL(k0_prep,   dim3(256), dim3(256), 0, stream, cb, bn, ebf, mask);
    hipLaunchKernelGGL(k1_score,  dim3(512), dim3(256), 0, stream, in, ebf, bn, mask);
    hipLaunchKernelGGL(k2_rerank, dim3(256), dim3(256), 0, stream, in, cb, bn, mask, win);
    hipLaunchKernelGGL(k3_gather, dim3(256), dim3(256), 0, stream, cb, win, out);
}